// Round 6
// baseline (206.901 us; speedup 1.0000x reference)
//
#include <hip/hip_runtime.h>
#include <stdint.h>

// IDCT (DCT-III, DREAMPlace scaling) via even/odd split, fully fused:
//   E[m][p] = sum_{n even} x[m][n]*c(n,p),  O[m][p] = sum_{n odd} ...,
//   out[p] = E+O, out[N-1-p] = E-O   (c(n,N-1-p) = (-1)^n c(n,p)).
// R6: R3's 128x128/BK=32 fused tile + DOUBLE-BUFFERED staging. The harness
// poisons ws/out between replays (L3-cold staging, ~900cyc HBM latency);
// prefetching tile k+1 after the barrier hides that latency behind the
// 32-MFMA compute phase. 64 KB LDS, 2 blocks/CU (grid 512 caps there).
// ws: [0,32MB) A' bf16 (even cols | odd cols), [32,40) Ce, [40,48) Co.

#define Md 4096
#define Nfull 4096
#define Ph 2048   // half output width
#define Kh 2048   // half reduction
#define BM 128
#define BN 128
#define BK 32
#define NK (Kh / BK)   // 64 iters

typedef short bf16x8 __attribute__((ext_vector_type(8)));
typedef float floatx4 __attribute__((ext_vector_type(4)));
typedef unsigned short ushort_t;

__device__ __forceinline__ ushort_t f2bf(float f) {
  union { float f; uint32_t u; } v; v.f = f;
  uint32_t u = v.u;
  return (ushort_t)((u + 0x7fffu + ((u >> 16) & 1u)) >> 16);
}

// blocks [0,8192): x fp32 -> bf16 even/odd column deinterleave.
// blocks [8192,12288): fill Ce[p][ne]=c(2ne,p), Co[p][no]=c(2no+1,p).
__global__ __launch_bounds__(256) void prep_kernel(const float* __restrict__ x,
                                                   ushort_t* __restrict__ A,
                                                   ushort_t* __restrict__ Ce,
                                                   ushort_t* __restrict__ Co) {
  int b = blockIdx.x;
  if (b < 8192) {
    int i = (b * 256 + threadIdx.x) * 8;
    int m = i >> 12;
    int j = i & 4095;
    float4 a = *(const float4*)(x + i);
    float4 c = *(const float4*)(x + i + 4);
    union { ushort_t us[4]; int2 v; } ev, od;
    ev.us[0] = f2bf(a.x); od.us[0] = f2bf(a.y);
    ev.us[1] = f2bf(a.z); od.us[1] = f2bf(a.w);
    ev.us[2] = f2bf(c.x); od.us[2] = f2bf(c.y);
    ev.us[3] = f2bf(c.z); od.us[3] = f2bf(c.w);
    int half = j >> 1;
    *(int2*)(A + m * Nfull + half) = ev.v;
    *(int2*)(A + m * Nfull + Ph + half) = od.v;
  } else {
    int idx = ((b - 8192) * 256 + threadIdx.x) * 8;  // [0, 8M)
    const float s = 3.14159265358979f / 8192.0f;     // pi/(2N)
    union { ushort_t us[8]; int4 v; } pk;
    if (idx < Ph * Kh) {               // Ce
      int p = idx >> 11;
      int ne0 = idx & 2047;
      int tp = 2 * p + 1;
#pragma unroll
      for (int jj = 0; jj < 8; ++jj) {
        int n = 2 * (ne0 + jj);
        int t = (n * tp) & 16383;      // mod 4N: exact int reduction
        float c = (n == 0) ? 1.0f : 2.0f * __cosf(s * (float)t);
        pk.us[jj] = f2bf(c);
      }
      *(int4*)(Ce + idx) = pk.v;
    } else {                           // Co
      int local = idx - Ph * Kh;
      int p = local >> 11;
      int no0 = local & 2047;
      int tp = 2 * p + 1;
#pragma unroll
      for (int jj = 0; jj < 8; ++jj) {
        int n = 2 * (no0 + jj) + 1;
        int t = (n * tp) & 16383;
        pk.us[jj] = f2bf(2.0f * __cosf(s * (float)t));
      }
      *(int4*)(Co + local) = pk.v;
    }
  }
}

// Fused dual GEMM + butterfly, double-buffered staging.
// Block tile 128m x 128p, BK=32. 4 waves 2x2: wave tile 64x64 per GEMM,
// frags 4x4, dual acc E/O (128 acc VGPRs). Per iter: 8 global_load_lds
// issues (prefetch, after barrier) + 32 ds_read_b128 + 32 MFMAs per wave.
__global__ __launch_bounds__(256, 2) void gemm_fused(const ushort_t* __restrict__ A,
                                                     const ushort_t* __restrict__ Ce,
                                                     const ushort_t* __restrict__ Co,
                                                     float* __restrict__ out) {
  // Linear tile order (row-major, 64B rows) — REQUIRED by global_load_lds
  // (wave-uniform base + lane*16B scatter), so no padding possible.
  __shared__ __align__(16) ushort_t AsE[2][BM * BK];   // 2 x 8 KB
  __shared__ __align__(16) ushort_t AsO[2][BM * BK];   // 2 x 8 KB
  __shared__ __align__(16) ushort_t BsE[2][BN * BK];   // 2 x 8 KB
  __shared__ __align__(16) ushort_t BsO[2][BN * BK];   // 2 x 8 KB -> 64 KB

  const int tid = threadIdx.x;
  const int wid = tid >> 6;
  const int lane = tid & 63;

  const int bm = blockIdx.y * BM;
  const int bn = blockIdx.x * BN;

  const int wm = (wid & 1) * 64;
  const int wn = (wid >> 1) * 64;

  const int lrow = lane & 15;
  const int kq = (lane >> 4) * 8;

  floatx4 accE[4][4] = {};
  floatx4 accO[4][4] = {};

  // Staging: tile = 128 rows x 64B = 8 KB -> 2 issues of 256 thr x 16B.
  // chunk c = issue*256+tid: row=c>>2, elem=(c&3)*8; LDS elem offset = 8c.
  const int r0 = tid >> 2, e0 = (tid & 3) * 8;
  const int r1 = r0 + 64;
  const int l0 = wid * 512;            // wave-uniform LDS base (elements)
  const int l1 = 2048 + wid * 512;

  // Per-thread global staging pointers, advanced by BK each iteration.
  const ushort_t* pAe0 = A + (size_t)(bm + r0) * Nfull + e0;
  const ushort_t* pAe1 = A + (size_t)(bm + r1) * Nfull + e0;
  const ushort_t* pAo0 = pAe0 + Ph;
  const ushort_t* pAo1 = pAe1 + Ph;
  const ushort_t* pBe0 = Ce + (size_t)(bn + r0) * Kh + e0;
  const ushort_t* pBe1 = Ce + (size_t)(bn + r1) * Kh + e0;
  const ushort_t* pBo0 = Co + (size_t)(bn + r0) * Kh + e0;
  const ushort_t* pBo1 = Co + (size_t)(bn + r1) * Kh + e0;

#define GLDS(src, dst) __builtin_amdgcn_global_load_lds( \
      (const __attribute__((address_space(1))) void*)(src), \
      (__attribute__((address_space(3))) void*)(dst), 16, 0, 0)

#define ISSUE(buf)                      \
  do {                                  \
    GLDS(pAe0, AsE[buf] + l0);          \
    GLDS(pAe1, AsE[buf] + l1);          \
    GLDS(pAo0, AsO[buf] + l0);          \
    GLDS(pAo1, AsO[buf] + l1);          \
    GLDS(pBe0, BsE[buf] + l0);          \
    GLDS(pBe1, BsE[buf] + l1);          \
    GLDS(pBo0, BsO[buf] + l0);          \
    GLDS(pBo1, BsO[buf] + l1);          \
    pAe0 += BK; pAe1 += BK; pAo0 += BK; pAo1 += BK; \
    pBe0 += BK; pBe1 += BK; pBo0 += BK; pBo1 += BK; \
  } while (0)

  ISSUE(0);  // prologue prefetch for k=0

  for (int k = 0; k < NK; ++k) {
    const int b = k & 1;
    // Barrier's vmcnt(0) waits on the buf-b prefetch issued one full
    // iteration ago (prologue for k=0) — latency mostly hidden.
    __syncthreads();
    if (k + 1 < NK) ISSUE(b ^ 1);      // prefetch next tile, no wait

    bf16x8 bE[4], bO[4];
#pragma unroll
    for (int f = 0; f < 4; ++f) {
      bE[f] = *(const bf16x8*)(BsE[b] + (wn + f * 16 + lrow) * BK + kq);
      bO[f] = *(const bf16x8*)(BsO[b] + (wn + f * 16 + lrow) * BK + kq);
    }
#pragma unroll
    for (int im = 0; im < 4; ++im) {
      bf16x8 aE = *(const bf16x8*)(AsE[b] + (wm + im * 16 + lrow) * BK + kq);
      bf16x8 aO = *(const bf16x8*)(AsO[b] + (wm + im * 16 + lrow) * BK + kq);
#pragma unroll
      for (int jn = 0; jn < 4; ++jn) {
        accE[im][jn] = __builtin_amdgcn_mfma_f32_16x16x32_bf16(aE, bE[jn], accE[im][jn], 0, 0, 0);
        accO[im][jn] = __builtin_amdgcn_mfma_f32_16x16x32_bf16(aO, bO[jn], accO[im][jn], 0, 0, 0);
      }
    }
    // No second barrier: next iteration's ISSUE writes buf b^1, which this
    // iteration never reads; the next __syncthreads() orders reads/writes
    // of the same buffer across waves (lgkmcnt drained there too).
  }
#undef ISSUE
#undef GLDS

  // Epilogue butterfly. C/D mapping: col=lane&15, row=(lane>>4)*4+r.
#pragma unroll
  for (int im = 0; im < 4; ++im) {
    int rb = bm + wm + im * 16 + (lane >> 4) * 4;
#pragma unroll
    for (int jn = 0; jn < 4; ++jn) {
      int p = bn + wn + jn * 16 + lrow;
      float* lo = out + (size_t)rb * Nfull + p;
      float* hi = out + (size_t)rb * Nfull + (Nfull - 1 - p);
#pragma unroll
      for (int r = 0; r < 4; ++r) {
        float e = accE[im][jn][r];
        float o = accO[im][jn][r];
        lo[(size_t)r * Nfull] = e + o;
        hi[(size_t)r * Nfull] = e - o;
      }
    }
  }
}

extern "C" void kernel_launch(void* const* d_in, const int* in_sizes, int n_in,
                              void* d_out, int out_size, void* d_ws, size_t ws_size,
                              hipStream_t stream) {
  const float* x = (const float*)d_in[0];
  float* out = (float*)d_out;
  ushort_t* Axb = (ushort_t*)d_ws;                     // 32 MB
  ushort_t* Ce = Axb + (size_t)Md * Nfull;             // 8 MB
  ushort_t* Co = Ce + (size_t)Ph * Kh;                 // 8 MB

  prep_kernel<<<12288, 256, 0, stream>>>(x, Axb, Ce, Co);

  dim3 grid(Ph / BN, Md / BM);  // 16 x 32 = 512 blocks = 2/CU
  gemm_fused<<<grid, 256, 0, stream>>>(Axb, Ce, Co, out);
}